// Round 3
// baseline (87.119 us; speedup 1.0000x reference)
//
#include <hip/hip_runtime.h>
#include <hip/hip_bf16.h>

#define NT 1024

constexpr int B_ = 16, N_ = 64, S_ = 4, F0_ = 8, C_ = 32;
constexpr int MAXE = 32;   // max neighbors/row; ~5 avg at 10% density, huge margin

typedef __attribute__((ext_vector_type(8))) short short8;
typedef __attribute__((ext_vector_type(4))) float f32x4;

__device__ __forceinline__ unsigned short f2bf(float x) {
    __hip_bfloat16 h = __float2bfloat16(x);
    return *reinterpret_cast<unsigned short*>(&h);
}

// Stage folded weights, bf16 transposed: wT[c][sf], sf = s*F+f,
// slots 0..3 = e-kernel, 4 = bias, 5 = root. Stride SFP (pad breaks 2^k).
template<int F, int SFP>
__device__ __forceinline__ void stage_w(int tid, const float* __restrict__ wk,
                                        const float* __restrict__ bk,
                                        const float* __restrict__ wr,
                                        unsigned short* wT) {
    constexpr int SF = 6 * F;
    for (int idx = tid; idx < C_ * SF; idx += NT) {
        int c = idx / SF, sf = idx - c * SF;
        int s = sf / F, f = sf - s * F;
        float v;
        if (s < 4)       v = wk[(s * C_ + c) * F + f];
        else if (s == 4) v = bk[c * F + f];
        else             v = wr[f * C_ + c];
        wT[c * SFP + sf] = f2bf(v);
    }
}

// Sparse gather: u[t][sf] over compacted neighbor lists (e pre-masked by a).
template<int F, int LOG2F, int SFP>
__device__ __forceinline__ void u_phase(int tid, const float* hin,
                                        const float4* ec4,
                                        const unsigned char* nbr_idx,
                                        const int* nbr_cnt,
                                        unsigned short* u_bf) {
    for (int pair = tid; pair < N_ * F; pair += NT) {
        int t = pair >> LOG2F;
        int f = pair & (F - 1);
        float u0 = 0.f, u1 = 0.f, u2 = 0.f, u3 = 0.f, u4 = 0.f;
        const int cnt = nbr_cnt[t];
        for (int j = 0; j < cnt; ++j) {
            int i = nbr_idx[t * MAXE + j];
            float hv = hin[i * F + f];
            float4 ev = ec4[t * MAXE + j];
            u0 = fmaf(ev.x, hv, u0);
            u1 = fmaf(ev.y, hv, u1);
            u2 = fmaf(ev.z, hv, u2);
            u3 = fmaf(ev.w, hv, u3);
            u4 += hv;
        }
        unsigned short* ut = u_bf + t * SFP;
        ut[0 * F + f] = f2bf(u0);
        ut[1 * F + f] = f2bf(u1);
        ut[2 * F + f] = f2bf(u2);
        ut[3 * F + f] = f2bf(u3);
        ut[4 * F + f] = f2bf(u4);
        ut[5 * F + f] = f2bf(hin[t * F + f]);
    }
}

// One 16x16 C-tile: A[m=lane&15][k=quad*8+j], B from transposed wT — both
// frags are single contiguous ds_read_b128s.
template<int SFP, int KSTEPS>
__device__ __forceinline__ f32x4 mfma_tile(int lane, int mt, int nt,
                                           const unsigned short* u_bf,
                                           const unsigned short* wT) {
    const int quad = lane >> 4, l16 = lane & 15;
    f32x4 acc = {0.f, 0.f, 0.f, 0.f};
    const unsigned short* arow = u_bf + (mt * 16 + l16) * SFP;
    const unsigned short* brow = wT + (nt * 16 + l16) * SFP;
#pragma unroll
    for (int kk = 0; kk < KSTEPS; ++kk) {
        const int kb = kk * 32 + quad * 8;
        short8 av = *reinterpret_cast<const short8*>(arow + kb);
        short8 bv = *reinterpret_cast<const short8*>(brow + kb);
        acc = __builtin_amdgcn_mfma_f32_16x16x32_bf16(av, bv, acc, 0, 0, 0);
    }
    return acc;
}

__global__ __launch_bounds__(NT) void ecc_fused(
    const float* __restrict__ x,  const float* __restrict__ a,  const float* __restrict__ e,
    const float* __restrict__ w1k, const float* __restrict__ b1k,
    const float* __restrict__ w1r, const float* __restrict__ b1v,
    const float* __restrict__ w2k, const float* __restrict__ b2k,
    const float* __restrict__ w2r, const float* __restrict__ b2v,
    const float* __restrict__ wd,  const float* __restrict__ bd,
    float* __restrict__ out)
{
    __shared__ float x_sh[N_ * F0_];
    __shared__ float mask_sh[N_];
    __shared__ float h_sh[N_ * C_];
    __shared__ __align__(16) unsigned short u1_bf[N_ * 72];    // SF=48, K-pad to 64
    __shared__ __align__(16) unsigned short u2_bf[N_ * 200];   // SF=192 exactly
    __shared__ __align__(16) unsigned short wT1[C_ * 72];
    __shared__ __align__(16) unsigned short wT2[C_ * 200];
    __shared__ __align__(16) float4 ec4[N_ * MAXE];
    __shared__ unsigned char nbr_idx[N_ * MAXE];
    __shared__ int nbr_cnt[N_];
    __shared__ float b1_sh[C_], b2_sh[C_], wd_sh[C_];
    __shared__ float red_sh[8];

    const int b   = blockIdx.x;
    const int tid = threadIdx.x;
    const float* eb  = e + (size_t)b * N_ * N_ * S_;
    const float* a_g = a + (size_t)b * N_ * N_;

    // ---- phase 0: ALL global loads issued here, latencies overlap ----
    // a + e rows, unconditionally (e is pre-masked by a, so rows with a==0
    // are zeros we simply don't store) -> a and e loads are independent.
    {
        const int wv = tid >> 6, lane = tid & 63;
        float  av[4];
        float4 ev[4];
#pragma unroll
        for (int r = 0; r < 4; ++r) {
            const int t = wv * 4 + r;
            av[r] = a_g[t * N_ + lane];
            ev[r] = *reinterpret_cast<const float4*>(eb + (size_t)(t * N_ + lane) * S_);
        }
#pragma unroll
        for (int r = 0; r < 4; ++r) {
            const int t = wv * 4 + r;
            const unsigned long long m = __ballot(av[r] != 0.f);
            if (lane == 0) {
                int cnt = (int)__popcll(m);
                nbr_cnt[t] = cnt > MAXE ? MAXE : cnt;
            }
            if (av[r] != 0.f) {
                int pos = (int)__popcll(m & ((1ull << lane) - 1ull));
                if (pos < MAXE) {
                    nbr_idx[t * MAXE + pos] = (unsigned char)lane;
                    ec4[t * MAXE + pos] = ev[r];
                }
            }
        }
    }
    // node features (8 ch) + validity mask (ch 8)
    for (int idx = tid; idx < N_ * (F0_ + 1); idx += NT) {
        int t = idx / 9, j = idx - t * 9;
        float v = x[(b * N_ + t) * 9 + j];
        if (j == F0_) mask_sh[t] = v;
        else          x_sh[t * F0_ + j] = v;
    }
    // both layers' folded weights + biases + head weights
    stage_w<8, 72>(tid, w1k, b1k, w1r, wT1);
    stage_w<32, 200>(tid, w2k, b2k, w2r, wT2);
    if (tid < C_) { b1_sh[tid] = b1v[tid]; b2_sh[tid] = b2v[tid]; wd_sh[tid] = wd[tid]; }
    // zero K-pad [48,64) for layer-1 operands
    for (int idx = tid; idx < (N_ + C_) * 16; idx += NT) {
        int row = idx >> 4, k = idx & 15;
        if (row < N_) u1_bf[row * 72 + 48 + k] = 0;
        else          wT1[(row - N_) * 72 + 48 + k] = 0;
    }
    __syncthreads();

    // ---- layer 1: u-phase (x_sh -> u1) ----
    u_phase<8, 3, 72>(tid, x_sh, ec4, nbr_idx, nbr_cnt, u1_bf);
    __syncthreads();

    // ---- layer 1: MFMA -> h_sh ----
    {
        const int wv = tid >> 6;
        if (wv < 8) {
            const int lane = tid & 63, quad = lane >> 4, l16 = lane & 15;
            const int mt = wv >> 1, nt = wv & 1;
            f32x4 acc = mfma_tile<72, 2>(lane, mt, nt, u1_bf, wT1);
            const int cc = nt * 16 + l16;
            const float bc = b1_sh[cc];
#pragma unroll
            for (int r = 0; r < 4; ++r) {
                const int tt = mt * 16 + quad * 4 + r;
                float v = (acc[r] + bc) * mask_sh[tt];
                h_sh[tt * C_ + cc] = v > 0.f ? v : 0.f;
            }
        }
    }
    __syncthreads();

    // ---- layer 2: u-phase (h_sh -> u2) ----
    u_phase<32, 5, 200>(tid, h_sh, ec4, nbr_idx, nbr_cnt, u2_bf);
    __syncthreads();

    // ---- layer 2: MFMA with fused pool+head epilogue (no h_sh round trip) ----
    {
        const int wv = tid >> 6;
        float partial = 0.f;
        if (wv < 8) {
            const int lane = tid & 63, quad = lane >> 4, l16 = lane & 15;
            const int mt = wv >> 1, nt = wv & 1;
            f32x4 acc = mfma_tile<200, 6>(lane, mt, nt, u2_bf, wT2);
            const int cc = nt * 16 + l16;
            const float bc = b2_sh[cc];
            const float wc = wd_sh[cc];
#pragma unroll
            for (int r = 0; r < 4; ++r) {
                const int tt = mt * 16 + quad * 4 + r;
                float v = (acc[r] + bc) * mask_sh[tt];
                partial += (v > 0.f ? v : 0.f) * wc;   // mask is 0/1: idempotent
            }
#pragma unroll
            for (int off = 32; off > 0; off >>= 1)
                partial += __shfl_down(partial, off, 64);
            if (lane == 0) red_sh[wv] = partial;
        }
    }
    __syncthreads();
    if (tid == 0) {
        float s = bd[0];
#pragma unroll
        for (int w = 0; w < 8; ++w) s += red_sh[w];
        out[b] = s;
    }
}

extern "C" void kernel_launch(void* const* d_in, const int* in_sizes, int n_in,
                              void* d_out, int out_size, void* d_ws, size_t ws_size,
                              hipStream_t stream) {
    ecc_fused<<<B_, NT, 0, stream>>>(
        (const float*)d_in[0],  (const float*)d_in[1],  (const float*)d_in[2],
        (const float*)d_in[3],  (const float*)d_in[4],  (const float*)d_in[5],
        (const float*)d_in[6],  (const float*)d_in[7],  (const float*)d_in[8],
        (const float*)d_in[9],  (const float*)d_in[10], (const float*)d_in[11],
        (const float*)d_in[12], (float*)d_out);
}

// Round 4
// 85.184 us; speedup vs baseline: 1.0227x; 1.0227x over previous
//
#include <hip/hip_runtime.h>
#include <hip/hip_bf16.h>

#define NT 1024

constexpr int B_ = 16, N_ = 64, S_ = 4, F0_ = 8, C_ = 32;

// LDS strides (elements). All chosen so 16-lane frag accesses are <=2-way.
constexpr int ESTR = 72;            // E/A operand rows [t][i]
constexpr int EMAT = N_ * ESTR;     // 4608 elems per 64x64 matrix
constexpr int XSTR = 40;            // X/H operand rows [i][k], K=32
constexpr int WSTR = 40;            // WcatT rows [n][k],  K=32
constexpr int PSTR = 72;            // P transposed rows [n][i], K(i)=64

typedef __attribute__((ext_vector_type(8))) short short8;
typedef __attribute__((ext_vector_type(4))) float f32x4;

__device__ __forceinline__ unsigned short f2bf(float x) {
    __hip_bfloat16 h = __float2bfloat16(x);
    return *reinterpret_cast<unsigned short*>(&h);
}
__device__ __forceinline__ float bf2f(unsigned short u) {
    unsigned int v = ((unsigned int)u) << 16;
    float f;
    __builtin_memcpy(&f, &v, 4);
    return f;
}

// Step A: P = H(64xK=32, rows XH) @ Wcat(32x192, given transposed WT[n][k]).
// 16 waves x (1 A-frag read + 3x(B-read + MFMA) + 3 transposed b64 writes).
// Output written bf16-transposed: Pb[n][i] (B-operand form for step B).
__device__ __forceinline__ void stepA(int wv, int lane,
                                      const unsigned short* XHm,
                                      const unsigned short* WT,
                                      unsigned short* Pb) {
    const int l16 = lane & 15, quad = lane >> 4;
    const int mt = wv & 3, nt0 = (wv >> 2) * 3;
    short8 av = *reinterpret_cast<const short8*>(XHm + (mt * 16 + l16) * XSTR + quad * 8);
#pragma unroll
    for (int q = 0; q < 3; ++q) {
        const int nt = nt0 + q;
        short8 bv = *reinterpret_cast<const short8*>(WT + (nt * 16 + l16) * WSTR + quad * 8);
        f32x4 acc = {0.f, 0.f, 0.f, 0.f};
        acc = __builtin_amdgcn_mfma_f32_16x16x32_bf16(av, bv, acc, 0, 0, 0);
        // D[row=i=quad*4+r][col=n=l16] -> Pb[nt*16+l16][mt*16+quad*4+r], 4 consec
        ushort4 pk;
        pk.x = f2bf(acc[0]); pk.y = f2bf(acc[1]);
        pk.z = f2bf(acc[2]); pk.w = f2bf(acc[3]);
        *reinterpret_cast<ushort4*>(Pb + (nt * 16 + l16) * PSTR + mt * 16 + quad * 4) = pk;
    }
}

// Step B core: acc(4) = Sigma_{s=0..4} (M_s @ P_s) tile for wave's (mt,nt).
// M_s = EA[s] (E0..E3, A), P_s = Pb rows [s*32 .. s*32+31].
__device__ __forceinline__ f32x4 stepB_mm(int wv, int lane,
                                          const unsigned short* EA,
                                          const unsigned short* Pb) {
    const int l16 = lane & 15, quad = lane >> 4;
    const int mt = wv >> 1, nt = wv & 1;
    f32x4 acc = {0.f, 0.f, 0.f, 0.f};
#pragma unroll
    for (int s = 0; s < 5; ++s) {
        const unsigned short* ar = EA + s * EMAT + (mt * 16 + l16) * ESTR;
        const unsigned short* br = Pb + (s * 32 + nt * 16 + l16) * PSTR;
#pragma unroll
        for (int kk = 0; kk < 2; ++kk) {
            short8 av = *reinterpret_cast<const short8*>(ar + kk * 32 + quad * 8);
            short8 bv = *reinterpret_cast<const short8*>(br + kk * 32 + quad * 8);
            acc = __builtin_amdgcn_mfma_f32_16x16x32_bf16(av, bv, acc, 0, 0, 0);
        }
    }
    return acc;
}

__global__ __launch_bounds__(NT) void ecc_fused(
    const float* __restrict__ x,  const float* __restrict__ a,  const float* __restrict__ e,
    const float* __restrict__ w1k, const float* __restrict__ b1k,
    const float* __restrict__ w1r, const float* __restrict__ b1v,
    const float* __restrict__ w2k, const float* __restrict__ b2k,
    const float* __restrict__ w2r, const float* __restrict__ b2v,
    const float* __restrict__ wd,  const float* __restrict__ bd,
    float* __restrict__ out)
{
    __shared__ __align__(16) unsigned short EA[5 * EMAT];     // E0..E3, A : 46 KB
    __shared__ __align__(16) unsigned short XH[N_ * XSTR];    // X, then H : 5 KB
    __shared__ __align__(16) unsigned short W1T[192 * WSTR];  // 15 KB
    __shared__ __align__(16) unsigned short W2T[192 * WSTR];  // 15 KB
    __shared__ __align__(16) unsigned short Pb[192 * PSTR];   // 27 KB
    __shared__ float mask_sh[N_];
    __shared__ float b1_sh[C_], b2_sh[C_], wd_sh[C_];
    __shared__ float red_sh[8];

    const int b   = blockIdx.x;
    const int tid = threadIdx.x;
    const int wv  = tid >> 6, lane = tid & 63;
    const float* eb = e + (size_t)b * N_ * N_ * S_;
    const float* ag = a + (size_t)b * N_ * N_;

    // ---- phase 0: stage everything (all global loads overlap) ----
    // e + a -> EA bf16, A-operand layout [s][t][i]
    {
        float4 ev[4];
        float  av[4];
#pragma unroll
        for (int r = 0; r < 4; ++r) {
            const int t = wv * 4 + r;
            ev[r] = *reinterpret_cast<const float4*>(eb + (size_t)(t * N_ + lane) * S_);
            av[r] = ag[t * N_ + lane];
        }
#pragma unroll
        for (int r = 0; r < 4; ++r) {
            const int t = wv * 4 + r;
            EA[0 * EMAT + t * ESTR + lane] = f2bf(ev[r].x);
            EA[1 * EMAT + t * ESTR + lane] = f2bf(ev[r].y);
            EA[2 * EMAT + t * ESTR + lane] = f2bf(ev[r].z);
            EA[3 * EMAT + t * ESTR + lane] = f2bf(ev[r].w);
            EA[4 * EMAT + t * ESTR + lane] = f2bf(av[r]);
        }
    }
    // x -> XH[t][0..7] + mask (contiguous global read)
    if (tid < N_ * 9) {
        const int t = tid / 9, j = tid - t * 9;
        const float v = x[(b * N_ + t) * 9 + j];
        if (j == F0_) mask_sh[t] = v;
        else          XH[t * XSTR + j] = f2bf(v);
    }
    // zero XH K-pad [8,32)
    for (int idx = tid; idx < N_ * 24; idx += NT) {
        const int t = idx / 24, k = idx - t * 24;
        XH[t * XSTR + 8 + k] = 0;
    }
    // folded weights, transposed bf16: WT[n=s*32+c][k=f]
    for (int idx = tid; idx < 192 * 32; idx += NT) {
        const int n = idx >> 5, k = idx & 31;
        const int s = n >> 5,  c = n & 31;
        float v1, v2;
        if (k >= F0_)    v1 = 0.f;
        else if (s < 4)  v1 = w1k[s * (C_ * F0_) + c * F0_ + k];
        else if (s == 4) v1 = b1k[c * F0_ + k];
        else             v1 = w1r[k * C_ + c];
        if (s < 4)       v2 = w2k[s * (C_ * C_) + c * C_ + k];
        else if (s == 4) v2 = b2k[c * C_ + k];
        else             v2 = w2r[k * C_ + c];
        W1T[n * WSTR + k] = f2bf(v1);
        W2T[n * WSTR + k] = f2bf(v2);
    }
    if (tid < C_) { b1_sh[tid] = b1v[tid]; b2_sh[tid] = b2v[tid]; wd_sh[tid] = wd[tid]; }
    __syncthreads();

    // ---- A1: P1 = X @ Wcat1 ----
    stepA(wv, lane, XH, W1T, Pb);
    __syncthreads();

    // ---- B1: h = relu(mask * (Sigma M_s@P_s + P_5 + b1)) -> XH (bf16 A-layout) ----
    if (wv < 8) {
        const int l16 = lane & 15, quad = lane >> 4;
        const int mt = wv >> 1, nt = wv & 1;
        f32x4 acc = stepB_mm(wv, lane, EA, Pb);
        const int c = nt * 16 + l16;
        ushort4 p5 = *reinterpret_cast<const ushort4*>(Pb + (160 + c) * PSTR + mt * 16 + quad * 4);
        const unsigned short p5a[4] = {p5.x, p5.y, p5.z, p5.w};
        const float bc = b1_sh[c];
#pragma unroll
        for (int r = 0; r < 4; ++r) {
            const int t = mt * 16 + quad * 4 + r;
            float v = (acc[r] + bc + bf2f(p5a[r])) * mask_sh[t];
            XH[t * XSTR + c] = f2bf(v > 0.f ? v : 0.f);
        }
    }
    __syncthreads();

    // ---- A2: P2 = H @ Wcat2 ----
    stepA(wv, lane, XH, W2T, Pb);
    __syncthreads();

    // ---- B2: msg2 + fused pool/head ----
    {
        float partial = 0.f;
        if (wv < 8) {
            const int l16 = lane & 15, quad = lane >> 4;
            const int mt = wv >> 1, nt = wv & 1;
            f32x4 acc = stepB_mm(wv, lane, EA, Pb);
            const int c = nt * 16 + l16;
            ushort4 p5 = *reinterpret_cast<const ushort4*>(Pb + (160 + c) * PSTR + mt * 16 + quad * 4);
            const unsigned short p5a[4] = {p5.x, p5.y, p5.z, p5.w};
            const float bc = b2_sh[c];
            const float wc = wd_sh[c];
#pragma unroll
            for (int r = 0; r < 4; ++r) {
                const int t = mt * 16 + quad * 4 + r;
                float v = (acc[r] + bc + bf2f(p5a[r])) * mask_sh[t];
                partial += (v > 0.f ? v : 0.f) * wc;
            }
#pragma unroll
            for (int off = 32; off > 0; off >>= 1)
                partial += __shfl_down(partial, off, 64);
            if (lane == 0) red_sh[wv] = partial;
        }
    }
    __syncthreads();
    if (tid == 0) {
        float s = bd[0];
#pragma unroll
        for (int w = 0; w < 8; ++w) s += red_sh[w];
        out[b] = s;
    }
}

extern "C" void kernel_launch(void* const* d_in, const int* in_sizes, int n_in,
                              void* d_out, int out_size, void* d_ws, size_t ws_size,
                              hipStream_t stream) {
    ecc_fused<<<B_, NT, 0, stream>>>(
        (const float*)d_in[0],  (const float*)d_in[1],  (const float*)d_in[2],
        (const float*)d_in[3],  (const float*)d_in[4],  (const float*)d_in[5],
        (const float*)d_in[6],  (const float*)d_in[7],  (const float*)d_in[8],
        (const float*)d_in[9],  (const float*)d_in[10], (const float*)d_in[11],
        (const float*)d_in[12], (float*)d_out);
}